// Round 1
// baseline (1494.602 us; speedup 1.0000x reference)
//
#include <hip/hip_runtime.h>
#include <math.h>

#define BB  4
#define NN  2000
#define TT  24
#define FIN 16
#define HH  128
#define EE  64000
#define CC  6
#define BN  (BB*NN)   // 8000

// ---------------- prep kernels ----------------
__global__ void transpose_kernel(const float* __restrict__ in, float* __restrict__ out,
                                 int R, int C) {
    int idx = blockIdx.x * 256 + threadIdx.x;
    if (idx < R * C) {
        int r = idx / C, c = idx - r * C;
        out[c * R + r] = in[idx];
    }
}

__global__ void deg_count_kernel(const int* __restrict__ dst, float* __restrict__ deg) {
    int e = blockIdx.x * 256 + threadIdx.x;
    if (e < EE) atomicAdd(&deg[dst[e]], 1.0f);
}

__global__ void dis_kernel(float* deg) {
    int n = blockIdx.x * 256 + threadIdx.x;
    if (n < NN) deg[n] = rsqrtf(fmaxf(deg[n], 1.0f));
}

__global__ void norm_kernel(const int* __restrict__ src, const int* __restrict__ dst,
                            const float* __restrict__ dis, float* __restrict__ norm) {
    int e = blockIdx.x * 256 + threadIdx.x;
    if (e < EE) norm[e] = dis[src[e]] * dis[dst[e]];
}

// ---------------- GRU ----------------
// 8 sequences per block, 128 threads. Thread j owns hidden unit j (rows j, j+128, j+256
// of the gate matrices). h is broadcast from LDS; W_hh comes pre-transposed [128][384]
// so the per-k loads are coalesced across threads.
__global__ __launch_bounds__(128) void gru_kernel(
    const float* __restrict__ x,       // [BN][TT][FIN]
    const float* __restrict__ Wt_hh,   // [HH][384]  (Wt[k][g] = W_hh[g][k])
    const float* __restrict__ W_ih,    // [384][FIN]
    const float* __restrict__ b_ih, const float* __restrict__ b_hh,
    float* __restrict__ temporal)      // [BN][HH]
{
    const int j = threadIdx.x;
    const int seq0 = blockIdx.x * 8;

    __shared__ __align__(16) float xs[TT][8][FIN];  // 12 KB
    __shared__ __align__(16) float hs[HH][8];       // 4 KB

    const float* xg = x + (size_t)seq0 * TT * FIN;
    for (int i = j; i < 8 * TT * FIN; i += 128) {
        int s = i / (TT * FIN);
        int rem = i - s * (TT * FIN);
        int t = rem / FIN;
        int f = rem - t * FIN;
        xs[t][s][f] = xg[i];
    }
    #pragma unroll
    for (int s = 0; s < 8; ++s) hs[j][s] = 0.0f;

    float wir[FIN], wiz[FIN], win[FIN];
    #pragma unroll
    for (int f = 0; f < FIN; ++f) {
        wir[f] = W_ih[(j      ) * FIN + f];
        wiz[f] = W_ih[(j + 128) * FIN + f];
        win[f] = W_ih[(j + 256) * FIN + f];
    }
    const float bir = b_ih[j], biz = b_ih[j + 128], bin_ = b_ih[j + 256];
    const float bhr = b_hh[j], bhz = b_hh[j + 128], bhn = b_hh[j + 256];

    __syncthreads();

    for (int t = 0; t < TT; ++t) {
        float ar[8], az[8], an[8];
        #pragma unroll
        for (int s = 0; s < 8; ++s) { ar[s] = bhr; az[s] = bhz; an[s] = bhn; }

        for (int k = 0; k < HH; ++k) {
            float wr = Wt_hh[k * 384 + j];
            float wz = Wt_hh[k * 384 + 128 + j];
            float wn = Wt_hh[k * 384 + 256 + j];
            float4 h0 = *(const float4*)&hs[k][0];
            float4 h1 = *(const float4*)&hs[k][4];
            float hv[8] = {h0.x, h0.y, h0.z, h0.w, h1.x, h1.y, h1.z, h1.w};
            #pragma unroll
            for (int s = 0; s < 8; ++s) {
                ar[s] = fmaf(wr, hv[s], ar[s]);
                az[s] = fmaf(wz, hv[s], az[s]);
                an[s] = fmaf(wn, hv[s], an[s]);
            }
        }

        float gr[8], gz[8], gn[8];
        #pragma unroll
        for (int s = 0; s < 8; ++s) { gr[s] = bir; gz[s] = biz; gn[s] = bin_; }
        #pragma unroll
        for (int s = 0; s < 8; ++s) {
            float4 x0 = *(const float4*)&xs[t][s][0];
            float4 x1 = *(const float4*)&xs[t][s][4];
            float4 x2 = *(const float4*)&xs[t][s][8];
            float4 x3 = *(const float4*)&xs[t][s][12];
            float xv[16] = {x0.x, x0.y, x0.z, x0.w, x1.x, x1.y, x1.z, x1.w,
                            x2.x, x2.y, x2.z, x2.w, x3.x, x3.y, x3.z, x3.w};
            #pragma unroll
            for (int f = 0; f < FIN; ++f) {
                gr[s] = fmaf(wir[f], xv[f], gr[s]);
                gz[s] = fmaf(wiz[f], xv[f], gz[s]);
                gn[s] = fmaf(win[f], xv[f], gn[s]);
            }
        }

        float hnew[8];
        #pragma unroll
        for (int s = 0; s < 8; ++s) {
            float vr = gr[s] + ar[s];
            float vz = gz[s] + az[s];
            float r = 1.0f / (1.0f + __expf(-vr));
            float z = 1.0f / (1.0f + __expf(-vz));
            float vn = gn[s] + r * an[s];
            float u = fminf(fmaxf(vn, -20.0f), 20.0f);
            float e2 = __expf(2.0f * u);
            float n = (e2 - 1.0f) / (e2 + 1.0f);
            hnew[s] = (1.0f - z) * n + z * hs[j][s];
        }
        __syncthreads();
        #pragma unroll
        for (int s = 0; s < 8; ++s) hs[j][s] = hnew[s];
        __syncthreads();
    }

    #pragma unroll
    for (int s = 0; s < 8; ++s)
        temporal[(size_t)(seq0 + s) * HH + j] = hs[j][s];
}

// ---------------- GCN scatter (atomic) ----------------
__global__ void scatter_kernel(const float* __restrict__ xin,   // [BB][NN][HH]
                               const int* __restrict__ src, const int* __restrict__ dst,
                               const float* __restrict__ norm,
                               float* __restrict__ agg)          // [BB][NN][HH], zeroed
{
    int tid = blockIdx.x * 256 + threadIdx.x;
    int e = tid >> 5;
    int hq = (tid & 31) << 2;
    if (e >= EE) return;
    int s = src[e], d = dst[e];
    float nm = norm[e];
    #pragma unroll
    for (int b = 0; b < BB; ++b) {
        const float* xp = xin + ((size_t)b * NN + s) * HH + hq;
        float4 v = *(const float4*)xp;
        float* ap = agg + ((size_t)b * NN + d) * HH + hq;
        atomicAdd(ap + 0, v.x * nm);
        atomicAdd(ap + 1, v.y * nm);
        atomicAdd(ap + 2, v.z * nm);
        atomicAdd(ap + 3, v.w * nm);
    }
}

// ---------------- linear + LayerNorm + ReLU ----------------
__global__ __launch_bounds__(128) void lin_ln_relu_kernel(
    const float* __restrict__ in,   // [BN][HH]
    const float* __restrict__ Wt,   // [HH][HH]  (Wt[k][j] = W[j][k])
    const float* __restrict__ bias,
    const float* __restrict__ gma, const float* __restrict__ bta,
    float* __restrict__ out)        // [BN][HH]
{
    const int j = threadIdx.x;
    const int r0 = blockIdx.x * 8;
    __shared__ __align__(16) float hb[HH][8];
    for (int i = j; i < 8 * HH; i += 128) {
        int r = i >> 7, k = i & 127;
        hb[k][r] = in[(size_t)(r0 + r) * HH + k];
    }
    __syncthreads();

    float acc[8];
    float bj = bias[j];
    #pragma unroll
    for (int r = 0; r < 8; ++r) acc[r] = bj;
    for (int k = 0; k < HH; ++k) {
        float w = Wt[k * HH + j];
        float4 a  = *(const float4*)&hb[k][0];
        float4 b4 = *(const float4*)&hb[k][4];
        acc[0] = fmaf(w, a.x,  acc[0]); acc[1] = fmaf(w, a.y,  acc[1]);
        acc[2] = fmaf(w, a.z,  acc[2]); acc[3] = fmaf(w, a.w,  acc[3]);
        acc[4] = fmaf(w, b4.x, acc[4]); acc[5] = fmaf(w, b4.y, acc[5]);
        acc[6] = fmaf(w, b4.z, acc[6]); acc[7] = fmaf(w, b4.w, acc[7]);
    }

    const int lane = j & 63, wid = j >> 6;
    __shared__ float red[2][8][2];
    float gj = gma[j], btj = bta[j];
    #pragma unroll
    for (int r = 0; r < 8; ++r) {
        float v = acc[r];
        float s1 = v, s2 = v * v;
        for (int off = 32; off >= 1; off >>= 1) {
            s1 += __shfl_down(s1, off);
            s2 += __shfl_down(s2, off);
        }
        if (lane == 0) { red[wid][r][0] = s1; red[wid][r][1] = s2; }
    }
    __syncthreads();
    #pragma unroll
    for (int r = 0; r < 8; ++r) {
        float s1 = red[0][r][0] + red[1][r][0];
        float s2 = red[0][r][1] + red[1][r][1];
        float mu = s1 * (1.0f / HH);
        float var = s2 * (1.0f / HH) - mu * mu;
        float rstd = rsqrtf(var + 1e-5f);
        float y = (acc[r] - mu) * rstd * gj + btj;
        out[(size_t)(r0 + r) * HH + j] = fmaxf(y, 0.0f);
    }
}

// ---------------- classifier (fused 2-layer MLP) ----------------
__global__ __launch_bounds__(128) void classifier_kernel(
    const float* __restrict__ tin,   // temporal [BN][HH]
    const float* __restrict__ sin_,  // spatial  [BN][HH]
    const float* __restrict__ Wt1,   // [2*HH][HH]  (Wt1[k][j] = cls_W1[j][k])
    const float* __restrict__ b1,
    const float* __restrict__ W2,    // [CC][HH]
    const float* __restrict__ b2,
    float* __restrict__ out)         // [BN][CC]
{
    const int j = threadIdx.x;
    const int r0 = blockIdx.x * 8;
    __shared__ __align__(16) float tb[HH][8];
    __shared__ __align__(16) float sb[HH][8];
    __shared__ __align__(16) float h1[HH][8];
    for (int i = j; i < 8 * HH; i += 128) {
        int r = i >> 7, k = i & 127;
        tb[k][r] = tin [(size_t)(r0 + r) * HH + k];
        sb[k][r] = sin_[(size_t)(r0 + r) * HH + k];
    }
    __syncthreads();

    float acc[8];
    float bj = b1[j];
    #pragma unroll
    for (int r = 0; r < 8; ++r) acc[r] = bj;
    for (int k = 0; k < HH; ++k) {
        float w = Wt1[k * HH + j];
        float4 a  = *(const float4*)&tb[k][0];
        float4 b4 = *(const float4*)&tb[k][4];
        acc[0] = fmaf(w, a.x,  acc[0]); acc[1] = fmaf(w, a.y,  acc[1]);
        acc[2] = fmaf(w, a.z,  acc[2]); acc[3] = fmaf(w, a.w,  acc[3]);
        acc[4] = fmaf(w, b4.x, acc[4]); acc[5] = fmaf(w, b4.y, acc[5]);
        acc[6] = fmaf(w, b4.z, acc[6]); acc[7] = fmaf(w, b4.w, acc[7]);
    }
    for (int k = 0; k < HH; ++k) {
        float w = Wt1[(HH + k) * HH + j];
        float4 a  = *(const float4*)&sb[k][0];
        float4 b4 = *(const float4*)&sb[k][4];
        acc[0] = fmaf(w, a.x,  acc[0]); acc[1] = fmaf(w, a.y,  acc[1]);
        acc[2] = fmaf(w, a.z,  acc[2]); acc[3] = fmaf(w, a.w,  acc[3]);
        acc[4] = fmaf(w, b4.x, acc[4]); acc[5] = fmaf(w, b4.y, acc[5]);
        acc[6] = fmaf(w, b4.z, acc[6]); acc[7] = fmaf(w, b4.w, acc[7]);
    }
    #pragma unroll
    for (int r = 0; r < 8; ++r) h1[j][r] = fmaxf(acc[r], 0.0f);
    __syncthreads();

    if (j < 8 * CC) {
        int r = j / CC, c = j - r * CC;
        float a = b2[c];
        for (int k = 0; k < HH; ++k) a = fmaf(W2[c * HH + k], h1[k][r], a);
        out[(size_t)(r0 + r) * CC + c] = a;
    }
}

// ---------------- launch ----------------
extern "C" void kernel_launch(void* const* d_in, const int* in_sizes, int n_in,
                              void* d_out, int out_size, void* d_ws, size_t ws_size,
                              hipStream_t stream) {
    const float* x    = (const float*)d_in[0];
    const int*   ei   = (const int*)  d_in[1];
    const float* W_ih = (const float*)d_in[2];
    const float* W_hh = (const float*)d_in[3];
    const float* b_ih = (const float*)d_in[4];
    const float* b_hh = (const float*)d_in[5];
    const float* gW1  = (const float*)d_in[6];
    const float* gb1  = (const float*)d_in[7];
    const float* gW2  = (const float*)d_in[8];
    const float* gb2  = (const float*)d_in[9];
    const float* lg1  = (const float*)d_in[10];
    const float* lb1  = (const float*)d_in[11];
    const float* lg2  = (const float*)d_in[12];
    const float* lb2  = (const float*)d_in[13];
    const float* cW1  = (const float*)d_in[14];
    const float* cb1  = (const float*)d_in[15];
    const float* cW2  = (const float*)d_in[16];
    const float* cb2  = (const float*)d_in[17];
    float* out = (float*)d_out;

    float* ws = (float*)d_ws;
    float* Wt_hh = ws;  ws += 128 * 384;
    float* Wt_g1 = ws;  ws += 128 * 128;
    float* Wt_g2 = ws;  ws += 128 * 128;
    float* Wt_c1 = ws;  ws += 256 * 128;
    float* deg   = ws;  ws += 2048;          // deg -> dis in place
    float* norm  = ws;  ws += EE;
    float* temporal = ws; ws += (size_t)BN * HH;
    float* agg   = ws;  ws += (size_t)BN * HH;
    float* sA    = ws;  ws += (size_t)BN * HH;
    float* sB    = ws;  ws += (size_t)BN * HH;

    const int* srcp = ei;
    const int* dstp = ei + EE;

    hipMemsetAsync(deg, 0, NN * sizeof(float), stream);

    transpose_kernel<<<(384 * 128 + 255) / 256, 256, 0, stream>>>(W_hh, Wt_hh, 384, 128);
    transpose_kernel<<<(128 * 128 + 255) / 256, 256, 0, stream>>>(gW1, Wt_g1, 128, 128);
    transpose_kernel<<<(128 * 128 + 255) / 256, 256, 0, stream>>>(gW2, Wt_g2, 128, 128);
    transpose_kernel<<<(128 * 256 + 255) / 256, 256, 0, stream>>>(cW1, Wt_c1, 128, 256);

    deg_count_kernel<<<(EE + 255) / 256, 256, 0, stream>>>(dstp, deg);
    dis_kernel<<<(NN + 255) / 256, 256, 0, stream>>>(deg);
    norm_kernel<<<(EE + 255) / 256, 256, 0, stream>>>(srcp, dstp, deg, norm);

    gru_kernel<<<BN / 8, 128, 0, stream>>>(x, Wt_hh, W_ih, b_ih, b_hh, temporal);

    hipMemsetAsync(agg, 0, (size_t)BN * HH * sizeof(float), stream);
    scatter_kernel<<<(EE * 32 + 255) / 256, 256, 0, stream>>>(temporal, srcp, dstp, norm, agg);
    lin_ln_relu_kernel<<<BN / 8, 128, 0, stream>>>(agg, Wt_g1, gb1, lg1, lb1, sA);

    hipMemsetAsync(agg, 0, (size_t)BN * HH * sizeof(float), stream);
    scatter_kernel<<<(EE * 32 + 255) / 256, 256, 0, stream>>>(sA, srcp, dstp, norm, agg);
    lin_ln_relu_kernel<<<BN / 8, 128, 0, stream>>>(agg, Wt_g2, gb2, lg2, lb2, sB);

    classifier_kernel<<<BN / 8, 128, 0, stream>>>(temporal, sB, Wt_c1, cb1, cW2, cb2, out);
}